// Round 4
// baseline (36239.011 us; speedup 1.0000x reference)
//
#include <hip/hip_runtime.h>
#include <hip/hip_cooperative_groups.h>
#include <stdint.h>

namespace cg = cooperative_groups;

// ---------------- problem sizes ----------------
constexpr int kB = 64, kT = 512, kD = 512, kH = 1024, kO = 256;

// ---------------- ws layout (bytes) ----------------
constexpr size_t OFF_U2   = 0;                                  // U2[t][b][u] f32 (128 MB) = x@W_in.T + b_in
constexpr size_t OFF_W4H1 = OFF_U2   + (size_t)kT*kB*kH*4;      // W_h1 tiled [j/4][u][4]
constexpr size_t OFF_W412 = OFF_W4H1 + (size_t)kH*kH*4;
constexpr size_t OFF_W4H2 = OFF_W412 + (size_t)kH*kH*4;
constexpr size_t OFF_WINT = OFF_W4H2 + (size_t)kH*kH*4;         // WinT[k][u] f32
constexpr size_t OFF_S1R  = OFF_WINT + (size_t)kD*kH*4;         // 2 x 1024 u64 rows (bit j%64, word j/64 per batch)
constexpr size_t OFF_S2R  = OFF_S1R  + 2*kH*8;
constexpr size_t OFF_CNT  = OFF_S2R  + 2*kH*8;                  // cnt[b][u] u32
// total ~142.5 MB

__device__ __forceinline__ uint64_t ld64(const uint64_t* p) {
  return __hip_atomic_load(p, __ATOMIC_RELAXED, __HIP_MEMORY_SCOPE_AGENT);
}
__device__ __forceinline__ void st64(uint64_t* p, uint64_t v) {
  __hip_atomic_store(p, v, __ATOMIC_RELAXED, __HIP_MEMORY_SCOPE_AGENT);
}
__device__ __forceinline__ uint64_t uni64(uint64_t x) {   // force wave-uniform into SGPRs
  uint32_t lo = __builtin_amdgcn_readfirstlane((uint32_t)x);
  uint32_t hi = __builtin_amdgcn_readfirstlane((uint32_t)(x >> 32));
  return ((uint64_t)hi << 32) | lo;
}

// ---------- W[1024][1024] -> W4[(j>>2)*1024 + u][4] (lane=u coalesced float4 over 4 consecutive j) ----------
__global__ void wtr4(const float* __restrict__ in, float* __restrict__ out) {
  int u = blockIdx.x;
  int j = blockIdx.y * 256 + threadIdx.x;
  float v = in[(size_t)u * kH + j];
  out[((size_t)(j >> 2) * kH + u) * 4 + (j & 3)] = v;
}

// ---------- transpose f32 in[R][C] -> out[C][R] ----------
__global__ void transpose_k(const float* __restrict__ in, float* __restrict__ out,
                            int R, int C) {
  __shared__ float tile[32][33];
  int c0 = blockIdx.x * 32, r0 = blockIdx.y * 32;
  int tx = threadIdx.x, ty = threadIdx.y;           // (32,8)
  for (int k = 0; k < 32; k += 8)
    tile[ty + k][tx] = in[(size_t)(r0 + ty + k) * C + c0 + tx];
  __syncthreads();
  for (int k = 0; k < 32; k += 8)
    out[(size_t)(c0 + ty + k) * R + r0 + tx] = tile[tx][ty + k];
}

// ---------- U2[t][b][u] = (sequential-k f32 fma chain of x[b][t][:]*W_in[u][:]) + b_in[u] ----------
__global__ __launch_bounds__(256) void uproj(const float* __restrict__ x,
                                             const float* __restrict__ WinT,
                                             const float* __restrict__ b_in,
                                             float* __restrict__ U2) {
  const int t    = blockIdx.x;                 // 512
  const int uc   = blockIdx.y;                 // 16
  const int lane = threadIdx.x & 63;
  const int wvu  = __builtin_amdgcn_readfirstlane(threadIdx.x >> 6);  // 0..3
  const int u    = uc * 64 + lane;
  const int b0   = wvu * 16;
  float acc[16];
  #pragma unroll
  for (int i = 0; i < 16; ++i) acc[i] = 0.0f;
  for (int k = 0; k < kD; k += 4) {
    float w0 = WinT[(size_t)(k + 0) * kH + u];
    float w1 = WinT[(size_t)(k + 1) * kH + u];
    float w2 = WinT[(size_t)(k + 2) * kH + u];
    float w3 = WinT[(size_t)(k + 3) * kH + u];
    #pragma unroll
    for (int bb = 0; bb < 16; ++bb) {
      const float4 xv = *(const float4*)(x + ((size_t)(b0 + bb) * kT + t) * kD + k);
      acc[bb] = __fmaf_rn(xv.x, w0, acc[bb]);   // ascending k, single chain: matches np sgemm
      acc[bb] = __fmaf_rn(xv.y, w1, acc[bb]);
      acc[bb] = __fmaf_rn(xv.z, w2, acc[bb]);
      acc[bb] = __fmaf_rn(xv.w, w3, acc[bb]);
    }
  }
  float bi = b_in[u];
  #pragma unroll
  for (int bb = 0; bb < 16; ++bb)
    U2[((size_t)t * kB + (b0 + bb)) * kH + u] = __fadd_rn(acc[bb], bi);
}

// sequential-j f32 chain over 1024 inputs; zero bits skipped (bit-exact: h+0==h, skip==include)
#define CHAIN1024(B, ROWS, W4) {                                        \
  _Pragma("unroll 1")                                                   \
  for (int jw = 0; jw < 16; ++jw) {                                     \
    uint64_t sw = ROWS[jw];                                             \
    if (!sw) continue;                                                  \
    const float4* wp = (const float4*)(W4) + (size_t)jw * 16 * kH + u;  \
    _Pragma("unroll")                                                   \
    for (int q = 0; q < 16; ++q) {                                      \
      float4 w4 = wp[(size_t)q * kH];                                   \
      B = __fadd_rn(B, ((sw >> (4*q + 0)) & 1) ? w4.x : 0.0f);          \
      B = __fadd_rn(B, ((sw >> (4*q + 1)) & 1) ? w4.y : 0.0f);          \
      B = __fadd_rn(B, ((sw >> (4*q + 2)) & 1) ? w4.z : 0.0f);          \
      B = __fadd_rn(B, ((sw >> (4*q + 3)) & 1) ? w4.w : 0.0f);          \
    }                                                                   \
  }                                                                     \
}

// ---------- persistent SNN: lane = unit, wave = (batch, unit-chunk); exact np-f32 emulation ----------
__global__ __launch_bounds__(512, 1) void snn4(
    const float* __restrict__ U2,
    const float* __restrict__ W4h1, const float* __restrict__ W412,
    const float* __restrict__ W4h2,
    const float* __restrict__ b_h1, const float* __restrict__ b_12,
    const float* __restrict__ b_h2,
    uint64_t* s1rows, uint64_t* s2rows, uint32_t* cnt2)
{
  cg::grid_group grid = cg::this_grid();
  const int tid  = threadIdx.x;
  const int lane = tid & 63;
  const int wvu  = __builtin_amdgcn_readfirstlane(tid >> 6);   // 0..7
  const bool isL1 = (wvu < 4);
  const int id = blockIdx.x * 4 + (isL1 ? wvu : wvu - 4);      // 0..1023
  const int b  = id & 63;                                      // batch
  const int c  = id >> 6;                                      // unit chunk 0..15
  const int u  = c * 64 + lane;                                // owned unit (lane-indexed)

  // zero both parities of both row buffers
  for (int i = blockIdx.x * 512 + tid; i < 2 * kH; i += 256 * 512) {
    st64(&s1rows[i], 0ull);
    st64(&s2rows[i], 0ull);
  }
  grid.sync();

  const float bh1 = b_h1[u];
  const float b12 = b_12[u];
  const float bh2 = b_h2[u];
  float v = 0.0f;
  uint32_t cnt = 0;

  for (int p = 0; p <= kT; ++p) {
    const uint64_t* r1g = s1rows + ((p & 1) ^ 1) * kH;   // s1 gen p-1
    const uint64_t* r2g = s2rows + (p & 1) * kH;         // s2 gen p-2
    uint64_t* w1g = s1rows + (p & 1) * kH;               // s1 gen p
    uint64_t* w2g = s2rows + ((p & 1) ^ 1) * kH;         // s2 gen p-1

    if (isL1) {
      if (p < kT) {
        uint64_t r1[16];
        #pragma unroll
        for (int jw = 0; jw < 16; ++jw) r1[jw] = uni64(ld64(&r1g[jw * 64 + b]));
        float A = U2[((size_t)p * kB + b) * kH + u];     // x@W_in.T + b_in (precomputed, exact order)
        float B = 0.0f;
        CHAIN1024(B, r1, W4h1)                           // s1(p-1)@W_h1.T, sequential j
        float h = __fadd_rn(__fadd_rn(A, B), bh1);       // ((x@W+b_in)+rec)+b_h1
        v = __fadd_rn(__fmul_rn(0.9f, v), h);            // BETA*v then +h, separately rounded
        bool s = (v >= 1.0f);
        if (s) v = __fsub_rn(v, 1.0f);
        uint64_t m = __ballot(s);                        // bits over lanes = units of chunk c
        if (lane == 0) st64(&w1g[c * 64 + b], m);
      }
    } else {
      if (p >= 1) {
        uint64_t r1[16], r2[16];
        #pragma unroll
        for (int jw = 0; jw < 16; ++jw) r1[jw] = uni64(ld64(&r1g[jw * 64 + b]));
        #pragma unroll
        for (int jw = 0; jw < 16; ++jw) r2[jw] = uni64(ld64(&r2g[jw * 64 + b]));
        float B1 = 0.0f;
        CHAIN1024(B1, r1, W412)                          // s1(t)@W_12.T
        float C = __fadd_rn(B1, b12);
        float B2 = 0.0f;
        CHAIN1024(B2, r2, W4h2)                          // s2(t-1)@W_h2.T
        float h = __fadd_rn(__fadd_rn(C, B2), bh2);      // ((mm+b_12)+mm2)+b_h2
        v = __fadd_rn(__fmul_rn(0.9f, v), h);
        bool s = (v >= 1.0f);
        if (s) { v = __fsub_rn(v, 1.0f); cnt++; }
        uint64_t m = __ballot(s);
        if (lane == 0) st64(&w2g[c * 64 + b], m);
      }
    }
    grid.sync();
  }

  if (!isL1) cnt2[(size_t)b * kH + u] = cnt;   // plain store; kernel boundary publishes
}

// ---------- exact f64 readout: out[b][o] = sum_j cnt[b][j]*W_out[o][j] + 512*b_out[o] ----------
__global__ void readout(const uint32_t* __restrict__ cnt2, const float* __restrict__ W_out,
                        const float* __restrict__ b_out, float* __restrict__ out) {
  const int b = blockIdx.x;    // 64
  const int o = threadIdx.x;   // 256
  double po = 512.0 * (double)b_out[o];
  for (int j = 0; j < kH; j += 4) {
    uint4  c4 = *(const uint4*)(cnt2 + (size_t)b * kH + j);
    float4 w4 = *(const float4*)(W_out + (size_t)o * kH + j);
    po = fma((double)c4.x, (double)w4.x, po);
    po = fma((double)c4.y, (double)w4.y, po);
    po = fma((double)c4.z, (double)w4.z, po);
    po = fma((double)c4.w, (double)w4.w, po);
  }
  out[(size_t)b * kO + o] = (float)po;
}

extern "C" void kernel_launch(void* const* d_in, const int* in_sizes, int n_in,
                              void* d_out, int out_size, void* d_ws, size_t ws_size,
                              hipStream_t stream) {
  (void)in_sizes; (void)n_in; (void)out_size; (void)ws_size;
  const float* x     = (const float*)d_in[0];
  const float* W_in  = (const float*)d_in[1];
  const float* pb_in = (const float*)d_in[2];
  const float* W_h1  = (const float*)d_in[3];
  const float* pb_h1 = (const float*)d_in[4];
  const float* W_12  = (const float*)d_in[5];
  const float* pb_12 = (const float*)d_in[6];
  const float* W_h2  = (const float*)d_in[7];
  const float* pb_h2 = (const float*)d_in[8];
  const float* W_out = (const float*)d_in[9];
  const float* pb_out= (const float*)d_in[10];
  float* out = (float*)d_out;

  char* ws = (char*)d_ws;
  float*    U2   = (float*)   (ws + OFF_U2);
  float*    W4h1 = (float*)   (ws + OFF_W4H1);
  float*    W412 = (float*)   (ws + OFF_W412);
  float*    W4h2 = (float*)   (ws + OFF_W4H2);
  float*    WinT = (float*)   (ws + OFF_WINT);
  uint64_t* s1r  = (uint64_t*)(ws + OFF_S1R);
  uint64_t* s2r  = (uint64_t*)(ws + OFF_S2R);
  uint32_t* cnt2 = (uint32_t*)(ws + OFF_CNT);

  hipLaunchKernelGGL(wtr4, dim3(kH, 4), dim3(256), 0, stream, W_h1, W4h1);
  hipLaunchKernelGGL(wtr4, dim3(kH, 4), dim3(256), 0, stream, W_12, W412);
  hipLaunchKernelGGL(wtr4, dim3(kH, 4), dim3(256), 0, stream, W_h2, W4h2);
  hipLaunchKernelGGL(transpose_k, dim3(kD / 32, kH / 32), dim3(32, 8), 0, stream,
                     W_in, WinT, kH, kD);
  hipLaunchKernelGGL(uproj, dim3(kT, 16), dim3(256), 0, stream, x, WinT, pb_in, U2);

  void* args[] = {(void*)&U2, (void*)&W4h1, (void*)&W412, (void*)&W4h2,
                  (void*)&pb_h1, (void*)&pb_12, (void*)&pb_h2,
                  (void*)&s1r, (void*)&s2r, (void*)&cnt2};
  hipLaunchCooperativeKernel((void*)snn4, dim3(256), dim3(512), args, 0, stream);

  hipLaunchKernelGGL(readout, dim3(kB), dim3(kO), 0, stream, cnt2, W_out, pb_out, out);
}

// Round 6
// 21043.069 us; speedup vs baseline: 1.7221x; 1.7221x over previous
//
#include <hip/hip_runtime.h>
#include <stdint.h>

// ---------------- problem sizes ----------------
constexpr int kB = 64, kT = 512, kD = 512, kH = 1024, kO = 256;

// ---------------- grid config ----------------
constexpr int NBLK = 256;   // block Z owns units 4Z..4Z+3 of L1 AND L2, all 64 batches
constexpr int NTHR = 192;   // wave 0: L1(Wh1)  wave 1: W12(+LIF2+combine)  wave 2: Wh2

// ---------------- ws layout (bytes) — total ~142.3 MB (== R4's proven footprint) ----------------
constexpr size_t OFF_U2   = 0;                                   // U2[t][b][u] f32 (128 MB) = x@W_in.T + b_in
constexpr size_t OFF_WINT = OFF_U2   + (size_t)kT*kB*kH*4;       // WinT[k][u] f32 (2 MB)
constexpr size_t OFF_WS1  = OFF_WINT + (size_t)kD*kH*4;          // Wh1 sliced [u/4][j][4] (4 MB)
constexpr size_t OFF_WS2  = OFF_WS1  + (size_t)kH*kH*4;          // W12 sliced
constexpr size_t OFF_WS3  = OFF_WS2  + (size_t)kH*kH*4;          // Wh2 sliced
constexpr size_t OFF_S1R  = OFF_WS3  + (size_t)kH*kH*4;          // 2 x 1024 u64 rows (bits=batch)
constexpr size_t OFF_S2R  = OFF_S1R  + 2*kH*8;
constexpr size_t OFF_CNT  = OFF_S2R  + 2*kH*8;                   // cnt[b][u] u32 (256 KB)
constexpr size_t OFF_BAR  = OFF_CNT  + (size_t)kB*kH*4;          // barrier (64 B)

// cross-block data via agent-scope atomics (per-XCD L2s not coherent)
__device__ __forceinline__ uint64_t ld64(const uint64_t* p) {
  return __hip_atomic_load(p, __ATOMIC_RELAXED, __HIP_MEMORY_SCOPE_AGENT);
}
__device__ __forceinline__ void st64(uint64_t* p, uint64_t v) {
  __hip_atomic_store(p, v, __ATOMIC_RELAXED, __HIP_MEMORY_SCOPE_AGENT);
}

// monotonic-generation grid barrier (validated: R2 custom barrier bit-matched R3 cg::sync)
__device__ __forceinline__ void gridbar(uint32_t* bar, uint32_t& mygen) {
  __syncthreads();
  if (threadIdx.x == 0) {
    uint32_t g = mygen + 1;
    uint32_t a = __hip_atomic_fetch_add(&bar[0], 1u, __ATOMIC_ACQ_REL, __HIP_MEMORY_SCOPE_AGENT);
    if (a == (uint32_t)(gridDim.x - 1)) {
      __hip_atomic_store(&bar[0], 0u, __ATOMIC_RELAXED, __HIP_MEMORY_SCOPE_AGENT);
      __hip_atomic_store(&bar[1], g,  __ATOMIC_RELEASE, __HIP_MEMORY_SCOPE_AGENT);
    } else {
      while (__hip_atomic_load(&bar[1], __ATOMIC_ACQUIRE, __HIP_MEMORY_SCOPE_AGENT) < g)
        __builtin_amdgcn_s_sleep(1);
    }
  }
  __syncthreads();
  mygen = mygen + 1;
}

// ---------- transpose f32 in[R][C] -> out[C][R] (for WinT) ----------
__global__ void transpose_k(const float* __restrict__ in, float* __restrict__ out,
                            int R, int C) {
  __shared__ float tile[32][33];
  int c0 = blockIdx.x * 32, r0 = blockIdx.y * 32;
  int tx = threadIdx.x, ty = threadIdx.y;           // (32,8)
  for (int k = 0; k < 32; k += 8)
    tile[ty + k][tx] = in[(size_t)(r0 + ty + k) * C + c0 + tx];
  __syncthreads();
  for (int k = 0; k < 32; k += 8)
    out[(size_t)(c0 + ty + k) * R + r0 + tx] = tile[tx][ty + k];
}

// ---------- W[1024][1024] -> sliced S[(u>>2)*1024 + j][4] with S[..][q] = W[4Z+q][j] ----------
__global__ void wtr_sl(const float* __restrict__ in, float* __restrict__ out) {
  int u = blockIdx.x;
  int j = blockIdx.y * 256 + threadIdx.x;
  float v = in[(size_t)u * kH + j];
  out[((size_t)(u >> 2) * kH + j) * 4 + (u & 3)] = v;
}

// ---------- U2[t][b][u] = x@W_in.T + b_in  (R4's bit-exact-proven kernel, unchanged) ----------
__global__ __launch_bounds__(256) void uproj(const float* __restrict__ x,
                                             const float* __restrict__ WinT,
                                             const float* __restrict__ b_in,
                                             float* __restrict__ U2) {
  const int t    = blockIdx.x;                 // 512
  const int uc   = blockIdx.y;                 // 16
  const int lane = threadIdx.x & 63;
  const int wvu  = __builtin_amdgcn_readfirstlane(threadIdx.x >> 6);  // 0..3
  const int u    = uc * 64 + lane;
  const int b0   = wvu * 16;
  float acc[16];
  #pragma unroll
  for (int i = 0; i < 16; ++i) acc[i] = 0.0f;
  for (int k = 0; k < kD; k += 4) {
    float w0 = WinT[(size_t)(k + 0) * kH + u];
    float w1 = WinT[(size_t)(k + 1) * kH + u];
    float w2 = WinT[(size_t)(k + 2) * kH + u];
    float w3 = WinT[(size_t)(k + 3) * kH + u];
    #pragma unroll
    for (int bb = 0; bb < 16; ++bb) {
      const float4 xv = *(const float4*)(x + ((size_t)(b0 + bb) * kT + t) * kD + k);
      acc[bb] = __fmaf_rn(xv.x, w0, acc[bb]);   // ascending k, single chain: np-exact
      acc[bb] = __fmaf_rn(xv.y, w1, acc[bb]);
      acc[bb] = __fmaf_rn(xv.z, w2, acc[bb]);
      acc[bb] = __fmaf_rn(xv.w, w3, acc[bb]);
    }
  }
  float bi = b_in[u];
  #pragma unroll
  for (int bb = 0; bb < 16; ++bb)
    U2[((size_t)t * kB + (b0 + bb)) * kH + u] = __fadd_rn(acc[bb], bi);
}

// sequential-j chain over 1024 spike-gated weights from LDS; bit-exact vs R4:
// fma(w, sf, B) with sf in {0,1} == fadd(B, bit?w:0); B starts +0 and RN cancellation
// yields +0, so B is never -0 and the ±0 corners coincide.
__device__ __forceinline__ void chain1024(const uint64_t* rows, const float4* wlds,
                                          int lane, float acc[4], float fone) {
  uint64_t cur = ld64(&rows[lane]);                     // group 0: lane L holds word j=L
  #pragma unroll 1
  for (int g = 0; g < 16; ++g) {
    uint64_t nxt = (g < 15) ? ld64(&rows[(g + 1) * 64 + lane]) : 0ull;  // prefetch next group
    uint32_t lo = (uint32_t)cur, hi = (uint32_t)(cur >> 32);
    #pragma unroll
    for (int jj = 0; jj < 64; ++jj) {
      uint32_t rlo = (uint32_t)__builtin_amdgcn_readlane((int)lo, jj);  // word for j=g*64+jj
      uint32_t rhi = (uint32_t)__builtin_amdgcn_readlane((int)hi, jj);
      uint64_t rw  = ((uint64_t)rhi << 32) | rlo;       // uniform -> SGPR pair
      float sf;
      asm("v_cndmask_b32 %0, 0, %1, %2" : "=v"(sf) : "v"(fone), "s"(rw));  // sf = bit(lane)
      float4 w4 = wlds[g * 64 + jj];                    // LDS broadcast read (uniform addr)
      acc[0] = __fmaf_rn(w4.x, sf, acc[0]);
      acc[1] = __fmaf_rn(w4.y, sf, acc[1]);
      acc[2] = __fmaf_rn(w4.z, sf, acc[2]);
      acc[3] = __fmaf_rn(w4.w, sf, acc[3]);
    }
    cur = nxt;
  }
}

// ---------- persistent SNN: lanes = batch, block Z owns units 4Z..4Z+3, weights LDS-resident ----------
__global__ __launch_bounds__(NTHR, 1) void snn6(
    const float* __restrict__ U2,
    const float* __restrict__ Wh1S, const float* __restrict__ W12S,
    const float* __restrict__ Wh2S,
    const float* __restrict__ b_h1, const float* __restrict__ b_12,
    const float* __restrict__ b_h2,
    uint64_t* s1rows, uint64_t* s2rows, uint32_t* cnt2, uint32_t* bar)
{
  __shared__ float4 ldsW[3][kH];   // 48 KB: per-role 4-unit weight slice, indexed by column j
  __shared__ float  xch[4][64];    // B2 exchange (Wh2 wave -> W12 wave)

  const int tid  = threadIdx.x;
  const int lane = tid & 63;                                          // batch
  const int wv   = __builtin_amdgcn_readfirstlane(tid >> 6);          // role 0/1/2
  const int Z    = blockIdx.x;
  uint32_t mygen = 0;
  const float fone = 1.0f;

  // ---- one-time: preload this role's 16 KB weight slice into LDS (coalesced)
  {
    const float* Wsrc = (wv == 0) ? Wh1S : (wv == 1) ? W12S : Wh2S;
    const float4* gs = (const float4*)Wsrc + (size_t)Z * kH;
    #pragma unroll
    for (int i = 0; i < 16; ++i) {
      int idx = i * 64 + lane;
      ldsW[wv][idx] = gs[idx];
    }
  }

  // ---- zero both generations of both spike-row buffers
  {
    int idx = Z * NTHR + tid;
    if (idx < 2 * kH) { st64(&s1rows[idx], 0ull); st64(&s2rows[idx], 0ull); }
  }
  gridbar(bar, mygen);   // also makes LDS preload visible block-wide

  float bA[4];           // role bias: b_h1 / b_12 / b_h2 for units 4Z..4Z+3
  float bh2v[4];         // W12 wave also needs b_h2 for the combine
  float v[4];            // membrane state per (unit q, batch lane)
  float B1[4];           // W12 wave: stashed partial across syncthreads
  uint32_t cnt[4] = {0, 0, 0, 0};
  #pragma unroll
  for (int q = 0; q < 4; ++q) {
    v[q] = 0.0f;
    B1[q] = 0.0f;
    bA[q]   = (wv == 0) ? b_h1[4 * Z + q] : (wv == 1) ? b_12[4 * Z + q] : b_h2[4 * Z + q];
    bh2v[q] = b_h2[4 * Z + q];
  }

  for (int p = 0; p <= kT; ++p) {
    const uint64_t* r1g = s1rows + ((p & 1) ^ 1) * kH;   // s1 gen p-1
    uint64_t*       w1g = s1rows + (p & 1) * kH;         // s1 gen p
    const uint64_t* r2g = s2rows + (p & 1) * kH;         // s2 gen p-2
    uint64_t*       w2g = s2rows + ((p & 1) ^ 1) * kH;   // s2 gen p-1

    if (wv == 0) {
      if (p < kT) {   // L1 step t=p
        // prefetch A early (no deps on the chain): 16B/lane, latency hidden by chain1024
        float4 A4 = *(const float4*)(U2 + ((size_t)p * kB + lane) * kH + 4 * Z);
        float acc[4] = {0.f, 0.f, 0.f, 0.f};
        chain1024(r1g, ldsW[0], lane, acc, fone);                // s1(p-1)@W_h1.T
        float A[4] = {A4.x, A4.y, A4.z, A4.w};
        #pragma unroll
        for (int q = 0; q < 4; ++q) {
          float h = __fadd_rn(__fadd_rn(A[q], acc[q]), bA[q]);   // ((x@W+b_in)+rec)+b_h1
          v[q] = __fadd_rn(__fmul_rn(0.9f, v[q]), h);
          bool s = (v[q] >= 1.0f);
          if (s) v[q] = __fsub_rn(v[q], 1.0f);
          uint64_t m = __ballot(s);                              // bits = batches
          if (lane == 0) st64(&w1g[4 * Z + q], m);
        }
      }
    } else if (wv == 1) {
      if (p >= 1) {   // L2 step t=p-1, part 1: B1 = s1(p-1)@W_12.T
        float acc[4] = {0.f, 0.f, 0.f, 0.f};
        chain1024(r1g, ldsW[1], lane, acc, fone);
        #pragma unroll
        for (int q = 0; q < 4; ++q) B1[q] = acc[q];
      }
    } else {
      if (p >= 1) {   // L2 part 2: B2 = s2(p-2)@W_h2.T
        float acc[4] = {0.f, 0.f, 0.f, 0.f};
        chain1024(r2g, ldsW[2], lane, acc, fone);
        #pragma unroll
        for (int q = 0; q < 4; ++q) xch[q][lane] = acc[q];
      }
    }
    __syncthreads();
    if (wv == 1 && p >= 1) {   // combine + LIF2 + publish (exact R4 op order)
      #pragma unroll
      for (int q = 0; q < 4; ++q) {
        float C = __fadd_rn(B1[q], bA[q]);                        // B1 + b_12
        float h = __fadd_rn(__fadd_rn(C, xch[q][lane]), bh2v[q]); // (C+B2)+b_h2
        v[q] = __fadd_rn(__fmul_rn(0.9f, v[q]), h);
        bool s = (v[q] >= 1.0f);
        if (s) { v[q] = __fsub_rn(v[q], 1.0f); cnt[q]++; }
        uint64_t m = __ballot(s);
        if (lane == 0) st64(&w2g[4 * Z + q], m);
      }
    }
    gridbar(bar, mygen);
  }

  if (wv == 1) {
    #pragma unroll
    for (int q = 0; q < 4; ++q) cnt2[(size_t)lane * kH + 4 * Z + q] = cnt[q];
  }
}

// ---------- exact f64 readout: out[b][o] = sum_j cnt[b][j]*W_out[o][j] + 512*b_out[o] ----------
__global__ void readout(const uint32_t* __restrict__ cnt2, const float* __restrict__ W_out,
                        const float* __restrict__ b_out, float* __restrict__ out) {
  const int b = blockIdx.x;    // 64
  const int o = threadIdx.x;   // 256
  double po = 512.0 * (double)b_out[o];
  for (int j = 0; j < kH; j += 4) {
    uint4  c4 = *(const uint4*)(cnt2 + (size_t)b * kH + j);
    float4 w4 = *(const float4*)(W_out + (size_t)o * kH + j);
    po = fma((double)c4.x, (double)w4.x, po);
    po = fma((double)c4.y, (double)w4.y, po);
    po = fma((double)c4.z, (double)w4.z, po);
    po = fma((double)c4.w, (double)w4.w, po);
  }
  out[(size_t)b * kO + o] = (float)po;
}

extern "C" void kernel_launch(void* const* d_in, const int* in_sizes, int n_in,
                              void* d_out, int out_size, void* d_ws, size_t ws_size,
                              hipStream_t stream) {
  (void)in_sizes; (void)n_in; (void)out_size; (void)ws_size;
  const float* x     = (const float*)d_in[0];
  const float* W_in  = (const float*)d_in[1];
  const float* pb_in = (const float*)d_in[2];
  const float* W_h1  = (const float*)d_in[3];
  const float* pb_h1 = (const float*)d_in[4];
  const float* W_12  = (const float*)d_in[5];
  const float* pb_12 = (const float*)d_in[6];
  const float* W_h2  = (const float*)d_in[7];
  const float* pb_h2 = (const float*)d_in[8];
  const float* W_out = (const float*)d_in[9];
  const float* pb_out= (const float*)d_in[10];
  float* out = (float*)d_out;

  char* ws = (char*)d_ws;
  float*    U2   = (float*)   (ws + OFF_U2);
  float*    WinT = (float*)   (ws + OFF_WINT);
  float*    Wh1S = (float*)   (ws + OFF_WS1);
  float*    W12S = (float*)   (ws + OFF_WS2);
  float*    Wh2S = (float*)   (ws + OFF_WS3);
  uint64_t* s1r  = (uint64_t*)(ws + OFF_S1R);
  uint64_t* s2r  = (uint64_t*)(ws + OFF_S2R);
  uint32_t* cnt2 = (uint32_t*)(ws + OFF_CNT);
  uint32_t* bar  = (uint32_t*)(ws + OFF_BAR);

  hipMemsetAsync(bar, 0, 64, stream);
  hipLaunchKernelGGL(transpose_k, dim3(kD / 32, kH / 32), dim3(32, 8), 0, stream,
                     W_in, WinT, kH, kD);
  hipLaunchKernelGGL(wtr_sl, dim3(kH, 4), dim3(256), 0, stream, W_h1, Wh1S);
  hipLaunchKernelGGL(wtr_sl, dim3(kH, 4), dim3(256), 0, stream, W_12, W12S);
  hipLaunchKernelGGL(wtr_sl, dim3(kH, 4), dim3(256), 0, stream, W_h2, Wh2S);
  hipLaunchKernelGGL(uproj, dim3(kT, 16), dim3(256), 0, stream, x, WinT, pb_in, U2);

  void* args[] = {(void*)&U2, (void*)&Wh1S, (void*)&W12S, (void*)&Wh2S,
                  (void*)&pb_h1, (void*)&pb_12, (void*)&pb_h2,
                  (void*)&s1r, (void*)&s2r, (void*)&cnt2, (void*)&bar};
  hipLaunchCooperativeKernel((void*)snn6, dim3(NBLK), dim3(NTHR), args, 0, stream);

  hipLaunchKernelGGL(readout, dim3(kB), dim3(kO), 0, stream, cnt2, W_out, pb_out, out);
}